// Round 9
// baseline (2626.335 us; speedup 1.0000x reference)
//
#include <hip/hip_runtime.h>

// B=256, T=64, F=32, ENC_U=256, DEC_U=512, VOCAB=2048, EMB=512, EPS=1e-3
// d_out = [16384 rows][2048 fp32 cols] = [16384][4096 u16 cols]. Region map:
//   fp32 cols    0..511 , all rows      : enc_out -> overwritten by decoder h
//   u16  cols 1024..2559, all rows      : E (fp16)  E[b,t'] = (enc*g1*INV)@Wxd_top
//   u16  cols 2560..3583, rows 0..8191  : keysT fp16 SCALED by 2*log2(e),
//                                         K=b*32768+n*64+tt -> row b*32+(n>>4)
//   u16  cols 2560..4095, rows 8192..10239 : EMBX fp16 [2048][1536]
//   u16  cols 2560..3583, rows 10240..10495: W2p  fp16 packed [k8][c][8]
//   u16  cols 2560..3583, rows 10496..11263: Bp   fp16 [n][k] = Wxd_top[k][n]*sg[k]
//   u16  cols 2560..3583, rows 11264..11519: W1p  fp16 [n][k] = W1[k][n]
//   u16  cols 2560..3583, rows 11520..11903: WhTp fp16 [dir][u][g][up] (encoder)
//   u16  cols 2560..3583, rows 11904..11951: WxTp fp16 [dir][g][fp][u][2]
// d_ws is not used.
static constexpr float INV_SQ = 0.99950037468777319f;  // 1/sqrt(1+1e-3)
static constexpr float TLN2E  = 2.8853900817779268f;   // 2*log2(e)

typedef __attribute__((ext_vector_type(8))) unsigned short us8;
typedef __attribute__((ext_vector_type(2))) unsigned short us2;
typedef __attribute__((ext_vector_type(8))) _Float16 f16x8;
typedef __attribute__((ext_vector_type(2))) _Float16 f16x2;
typedef __attribute__((ext_vector_type(4))) float f32x4;

__device__ __forceinline__ float h2f(unsigned short u) {
    union { unsigned short q; _Float16 h; } cv; cv.q = u; return (float)cv.h;
}
__device__ __forceinline__ unsigned short f2h(float x) {
    union { _Float16 h; unsigned short u; } cv; cv.h = (_Float16)x; return cv.u;
}
__device__ __forceinline__ float sigm(float x) { return 1.0f / (1.0f + __expf(-x)); }
__device__ __forceinline__ float fdot2f(f16x2 a, f16x2 b, float c) {
#if __has_builtin(__builtin_amdgcn_fdot2)
    return __builtin_amdgcn_fdot2(a, b, c, false);
#else
    return c + (float)a[0] * (float)b[0] + (float)a[1] * (float)b[1];
#endif
}
__device__ __forceinline__ float aexp2(float x) {
#if __has_builtin(__builtin_amdgcn_exp2f)
    return __builtin_amdgcn_exp2f(x);
#else
    return exp2f(x);
#endif
}
__device__ __forceinline__ float arcp(float x) {
#if __has_builtin(__builtin_amdgcn_rcpf)
    return __builtin_amdgcn_rcpf(x);
#else
    return 1.0f / x;
#endif
}

// ---------------------------------------------------------------------------
// Pack encoder weights fp16 into d_out (before enc_gru).
// ---------------------------------------------------------------------------
__global__ __launch_bounds__(512)
void repack_enc(float* __restrict__ out,
                const float* __restrict__ WhF, const float* __restrict__ WhB,
                const float* __restrict__ WxF, const float* __restrict__ WxB)
{
    unsigned short* up = (unsigned short*)out;
    const int id = blockIdx.x * 512 + threadIdx.x;   // grid 864 -> 442368
    if (id < 393216) {
        const int dir = (id >= 196608) ? 1 : 0;
        const int r = id - dir * 196608;
        const int u = r / 768;
        const int rr = r - u * 768;
        const int g = rr >> 8, upp = rr & 255;
        const float v = (dir ? WhB : WhF)[upp * 768 + g * 256 + u];
        up[(size_t)(11520 + (id >> 10)) * 4096 + 2560 + (id & 1023)] = f2h(v);
    } else if (id < 442368) {
        const int x = id - 393216;
        const int dir = (x >= 24576) ? 1 : 0;
        const int r = x - dir * 24576;
        const int g = r >> 13;
        const int r2 = r & 8191;
        const int fp = r2 >> 9;
        const int r3 = r2 & 511;
        const int u = r3 >> 1, j = r3 & 1;
        const float v = (dir ? WxB : WxF)[(fp * 2 + j) * 768 + g * 256 + u];
        up[(size_t)(11904 + (x >> 10)) * 4096 + 2560 + (x & 1023)] = f2h(v);
    }
}

// ---------------------------------------------------------------------------
// Encoder: persistent bidirectional GRU, 768 threads = (u, gate).
// Wh slice register-resident (32 us8/thread); h fp16 in LDS for dot2;
// GRU memory path fp32 in hsF; Wx fp16 staged in LDS.
// ---------------------------------------------------------------------------
__global__ __launch_bounds__(768, 1)
void enc_gru(const float* __restrict__ x,
             const float* __restrict__ g_e, const float* __restrict__ b_e,
             const float* __restrict__ bxF, const float* __restrict__ bhF,
             const float* __restrict__ bxB, const float* __restrict__ bhB,
             float* __restrict__ out)
{
    const int tid = threadIdx.x;
    const int dir = blockIdx.x & 1;
    const int b0  = (blockIdx.x >> 1) * 2;
    const int u = tid & 255, g = tid >> 8;   // g in 0..2

    const float* bx = dir ? bxB : bxF;
    const float* bh = dir ? bhB : bhF;

    __shared__ us2 WxL[12288];                           // [g][fp][u] 48 KiB
    __shared__ __align__(16) unsigned short hsH[2][256]; // h fp16 (matvec in)
    __shared__ float hsF[2][256];                        // h fp32 (memory path)
    __shared__ float part[4][2][256];                    // z, r, nx, nh
    __shared__ __align__(16) unsigned short xsH[2][32];

    const unsigned short* u16p = (const unsigned short*)out;

    for (int i = 0; i < 16; ++i) {
        const int fi = dir * 24576 + (tid * 16 + i) * 2;   // u16 flat
        const size_t a = (size_t)(11904 + (fi >> 10)) * 4096 + 2560 + (fi & 1023);
        WxL[tid * 16 + i] = *reinterpret_cast<const us2*>(u16p + a);
    }
    us8 ebw[32];
    {
        const int base = dir * 196608 + (u * 3 + g) * 256;   // u16 flat
        #pragma unroll
        for (int k = 0; k < 32; ++k) {
            const int fi = base + k * 8;
            const size_t a = (size_t)(11520 + (fi >> 10)) * 4096 + 2560 + (fi & 1023);
            ebw[k] = *reinterpret_cast<const us8*>(u16p + a);
        }
    }
    if (tid < 256) {
        hsF[0][tid] = 0.0f; hsF[1][tid] = 0.0f;
        hsH[0][tid] = 0;    hsH[1][tid] = 0;
    }
    const float bxg = bx[g * 256 + u], bhg = bh[g * 256 + u];
    __syncthreads();

    for (int t = 0; t < 64; ++t) {
        const int ts = dir ? (63 - t) : t;
        if (tid < 64) {
            const int f = tid & 31, bs = tid >> 5;
            xsH[bs][f] = f2h(x[((b0 + bs) * 64 + ts) * 32 + f] * (g_e[f] * INV_SQ) + b_e[f]);
        }
        __syncthreads();                                   // B1: xsH (+prev hsH)

        float ax0 = bxg, ax1 = bxg, ah0 = bhg, ah1 = bhg;
        {
            const us2* xs0 = reinterpret_cast<const us2*>(&xsH[0][0]);
            const us2* xs1 = reinterpret_cast<const us2*>(&xsH[1][0]);
            #pragma unroll
            for (int fp = 0; fp < 16; ++fp) {
                union { us2 q; f16x2 h; } w, a0, a1;
                w.q = WxL[(g * 16 + fp) * 256 + u];
                a0.q = xs0[fp]; a1.q = xs1[fp];
                ax0 = fdot2f(w.h, a0.h, ax0);
                ax1 = fdot2f(w.h, a1.h, ax1);
            }
        }
        #pragma unroll
        for (int k = 0; k < 32; ++k) {
            union { us8 q; f16x2 p[4]; } w, h0, h1;
            w.q = ebw[k];
            h0.q = *reinterpret_cast<const us8*>(&hsH[0][k * 8]);
            h1.q = *reinterpret_cast<const us8*>(&hsH[1][k * 8]);
            #pragma unroll
            for (int j = 0; j < 4; ++j) {
                ah0 = fdot2f(w.p[j], h0.p[j], ah0);
                ah1 = fdot2f(w.p[j], h1.p[j], ah1);
            }
        }
        if (g < 2) {
            part[g][0][u] = ax0 + ah0;
            part[g][1][u] = ax1 + ah1;
        } else {
            part[2][0][u] = ax0; part[2][1][u] = ax1;   // xh + bx_h
            part[3][0][u] = ah0; part[3][1][u] = ah1;   // hn + bh_n
        }
        __syncthreads();                                   // B2: part
        if (tid < 512) {
            const int bs = tid >> 8, uu = tid & 255;
            const float z = sigm(part[0][bs][uu]);
            const float r = sigm(part[1][bs][uu]);
            const float n = tanhf(part[2][bs][uu] + r * part[3][bs][uu]);
            const float hp = hsF[bs][uu];
            const float h = z * hp + (1.0f - z) * n;
            hsF[bs][uu] = h;
            hsH[bs][uu] = f2h(h);
            out[((b0 + bs) * 64 + ts) * 2048 + dir * 256 + uu] = h;
        }
        __syncthreads();                                   // B3: hsH/hsF
    }
}

// ---------------------------------------------------------------------------
// EMBX[v,n] = ((emb[v]*g2+beta2) @ Wxd_bot)[n] + (beta1 @ Wxd_top)[n] + bx_d[n]
// fp16 at row 8192+v, u16 col 2560+n. grid (128,3).
// ---------------------------------------------------------------------------
__global__ __launch_bounds__(256)
void embx_k(float* __restrict__ out, const float* __restrict__ emb,
            const float* __restrict__ g, const float* __restrict__ be,
            const float* __restrict__ Wxd, const float* __restrict__ bxd)
{
    __shared__ __align__(16) float As[16 * 512];
    const int tid = threadIdx.x;
    const int r0  = blockIdx.x * 16;
    const int n0  = blockIdx.y * 512;

    #pragma unroll
    for (int i = 0; i < 32; ++i) {
        const int idx = tid + i * 256;
        const int r = idx >> 9, k = idx & 511;
        As[idx] = emb[(r0 + r) * 512 + k] * (g[512 + k] * INV_SQ) + be[512 + k];
    }
    __syncthreads();

    const int n1 = n0 + tid, n2 = n0 + tid + 256;
    float cv1 = bxd[n1], cv2 = bxd[n2];
    for (int i = 0; i < 512; ++i) {
        const float bi = be[i];
        cv1 += bi * Wxd[i * 1536 + n1];
        cv2 += bi * Wxd[i * 1536 + n2];
    }

    float acc1[16], acc2[16];
    #pragma unroll
    for (int r = 0; r < 16; ++r) { acc1[r] = cv1; acc2[r] = cv2; }

    for (int k = 0; k < 512; k += 4) {
        float w1[4], w2[4];
        #pragma unroll
        for (int kk = 0; kk < 4; ++kk) {
            w1[kk] = Wxd[(512 + k + kk) * 1536 + n1];
            w2[kk] = Wxd[(512 + k + kk) * 1536 + n2];
        }
        #pragma unroll
        for (int r = 0; r < 16; ++r) {
            const float4 a = *reinterpret_cast<const float4*>(&As[r * 512 + k]);
            acc1[r] += a.x * w1[0] + a.y * w1[1] + a.z * w1[2] + a.w * w1[3];
            acc2[r] += a.x * w2[0] + a.y * w2[1] + a.z * w2[2] + a.w * w2[3];
        }
    }

    unsigned short* up = (unsigned short*)out;
    #pragma unroll
    for (int r = 0; r < 16; ++r) {
        const size_t base = (size_t)(8192 + r0 + r) * 4096 + 2560;
        up[base + n1] = f2h(acc1[r]);
        up[base + n2] = f2h(acc2[r]);
    }
}

// ---------------------------------------------------------------------------
// Repack weights into fp16 tiles inside d_out.
// ---------------------------------------------------------------------------
__global__ __launch_bounds__(512)
void repack_k(float* __restrict__ out, const float* __restrict__ W2,
              const float* __restrict__ Wxd, const float* __restrict__ W1,
              const float* __restrict__ g1)
{
    unsigned short* up = (unsigned short*)out;
    const int id = blockIdx.x * 512 + threadIdx.x;   // grid 2560 -> 1,310,720
    if (id < 262144) {
        const int k8 = id >> 12, rem = id & 4095, c = rem >> 3, j = rem & 7;
        up[(size_t)(10240 + (id >> 10)) * 4096 + 2560 + (id & 1023)] =
            f2h(W2[(k8 * 8 + j) * 512 + c]);
    } else if (id < 1048576) {
        const int x = id - 262144;
        const int n = x >> 9, k = x & 511;
        up[(size_t)(10496 + (x >> 10)) * 4096 + 2560 + (x & 1023)] =
            f2h(Wxd[k * 1536 + n] * (g1[k] * INV_SQ));
    } else {
        const int x = id - 1048576;
        const int n = x >> 9, k = x & 511;
        up[(size_t)(11264 + (x >> 10)) * 4096 + 2560 + (x & 1023)] =
            f2h(W1[k * 512 + n]);
    }
}

// ---------------------------------------------------------------------------
// MFMA GEMM, 64-row A tile (enc rows, fp32 cols 0..511 -> fp16 LDS, swizzled).
// MODE 0: E = enc @ Bp           -> fp16, u16 col 1024+n, same row.   NT=24
// MODE 2: keysT = (enc @ W1p + b1)*TLN2E -> fp16 transposed keysT.    NT=8
//         (scale folds tanh's 2*log2e into the stored keys; consumed
//          ONLY by the decoder score phase)
// ---------------------------------------------------------------------------
template <int MODE>
__global__ __launch_bounds__(256, 2)
void gemm64(float* __restrict__ out, const float* __restrict__ bias)
{
    constexpr int NT   = (MODE == 0) ? 24 : 8;
    constexpr int BROW = (MODE == 0) ? 10496 : 11264;
    const int tid = threadIdx.x;
    const int wid = tid >> 6, lane = tid & 63;
    const int row16 = lane & 15, kg = lane >> 4;
    const int m0 = blockIdx.x * 64;
    const unsigned short* u16p = (const unsigned short*)out;
    unsigned short* up = (unsigned short*)out;

    __shared__ __align__(16) char aL[65536];   // [64 m][512 k] fp16, xor-swizzled

    for (int i = tid; i < 8192; i += 256) {
        const int m = i >> 7, k4 = (i & 127) << 2;
        const float4 v = *reinterpret_cast<const float4*>(out + (size_t)(m0 + m) * 2048 + k4);
        union { unsigned long long u64; _Float16 h[4]; } p;
        p.h[0] = (_Float16)v.x; p.h[1] = (_Float16)v.y;
        p.h[2] = (_Float16)v.z; p.h[3] = (_Float16)v.w;
        const int off = (m * 1024 + k4 * 2) ^ ((m & 7) << 4);
        *reinterpret_cast<unsigned long long*>(aL + off) = p.u64;
    }
    __syncthreads();

    for (int i = 0; i < NT / 4; ++i) {
        const int nt = i * 4 + wid;
        const int n0t = nt * 64;
        f32x4 acc[4][4];
        #pragma unroll
        for (int mi = 0; mi < 4; ++mi)
            #pragma unroll
            for (int ni = 0; ni < 4; ++ni) {
                f32x4 z = {0.f, 0.f, 0.f, 0.f};
                acc[mi][ni] = z;
            }
        size_t bb[4];
        #pragma unroll
        for (int ni = 0; ni < 4; ++ni) {
            const int n = n0t + ni * 16 + row16;
            bb[ni] = (size_t)(BROW + (n >> 1)) * 4096 + 2560 + (n & 1) * 512 + kg * 8;
        }
        #pragma unroll 2
        for (int k0 = 0; k0 < 512; k0 += 32) {
            f16x8 af[4], bfr[4];
            #pragma unroll
            for (int mi = 0; mi < 4; ++mi) {
                const int row = mi * 16 + row16;
                const int off = (row * 1024 + (k0 + kg * 8) * 2) ^ ((row & 7) << 4);
                af[mi] = *reinterpret_cast<const f16x8*>(aL + off);
            }
            #pragma unroll
            for (int ni = 0; ni < 4; ++ni)
                bfr[ni] = *reinterpret_cast<const f16x8*>(u16p + bb[ni] + k0);
            #pragma unroll
            for (int mi = 0; mi < 4; ++mi)
                #pragma unroll
                for (int ni = 0; ni < 4; ++ni)
                    acc[mi][ni] = __builtin_amdgcn_mfma_f32_16x16x32_f16(
                        af[mi], bfr[ni], acc[mi][ni], 0, 0, 0);
        }
        #pragma unroll
        for (int mi = 0; mi < 4; ++mi) {
            #pragma unroll
            for (int ni = 0; ni < 4; ++ni) {
                const int n = n0t + ni * 16 + row16;
                if constexpr (MODE == 0) {
                    #pragma unroll
                    for (int r = 0; r < 4; ++r)
                        up[(size_t)(m0 + mi * 16 + kg * 4 + r) * 4096 + 1024 + n] =
                            f2h(acc[mi][ni][r]);
                } else {
                    const float bv = bias[n];
                    #pragma unroll
                    for (int r = 0; r < 4; ++r) {
                        const int ttm = mi * 16 + kg * 4 + r;
                        up[(size_t)(blockIdx.x * 32 + (n >> 4)) * 4096 + 2560 +
                           ((n & 15) << 6) + ttm] = f2h((acc[mi][ni][r] + bv) * TLN2E);
                    }
                }
            }
        }
    }
}

// ---------------------------------------------------------------------------
// Decoder: persistent per-batch, 512 threads, launch_bounds(512,1).
//  - keys REGISTER-RESIDENT: thread (tq,tt) holds keys[tq*64..+64][tt] as
//    64 f32 VGPRs (pre-scaled by 2*log2e in gemm64<2>); keysL LDS deleted.
//  - score: tanh(x) = 1 - 2/(exp2(k'+q')+1); per-iter add+exp2+add+rcp+fma,
//    no clamp (exp2->inf->rcp->0 saturates correctly); sum(V) hoisted.
//  - q matvec via v_dot2_f32_f16; all-wave shuffle softmax; EMBX prefetch.
//  - E slice register-resident: 96 us2. VGPR ~195 < 256 cap (2 waves/SIMD).
// ---------------------------------------------------------------------------
__global__ __launch_bounds__(512, 1)
void decoder(float* __restrict__ out,
             const float* __restrict__ b2,
             const float* __restrict__ V, const float* __restrict__ bV,
             const float* __restrict__ bh_d, const int* __restrict__ targ)
{
    const int b = blockIdx.x, tid = threadIdx.x;
    __shared__ __align__(16) unsigned short hsH[512];       // h as fp16
    __shared__ float qs2[512], Vm2[512];
    __shared__ float part[8][64], wv[64];
    __shared__ float xpP[2][1536];
    __shared__ int   tokL[64];

    float* erow = out + (size_t)b * 131072;
    const unsigned short* u16p = (const unsigned short*)out;

    // dec_h0 = concat(fwd final (t=63, cols<256), bwd final (t=0, cols>=256))
    hsH[tid] = f2h((tid < 256) ? erow[63 * 2048 + tid] : erow[tid]);
    Vm2[tid] = -2.0f * V[tid];
    if (tid < 64) tokL[tid] = targ[b * 64 + tid];
    const float b2c = b2[tid];
    const float bhz = bh_d[tid], bhr = bh_d[512 + tid], bhn = bh_d[1024 + tid];
    const float bVv = bV[0];
    const int lo7 = tid & 127, hi3 = tid >> 7;
    const size_t w2base = (size_t)(10240 + hi3) * 4096 + 2560 + lo7 * 8;

    // keys register-resident (scaled by TLN2E at the gemm64<2> epilogue)
    const int tt = tid & 63, tq = tid >> 6;
    float kreg[64];
    #pragma unroll
    for (int i = 0; i < 64; ++i) {
        const int n = tq * 64 + i;
        kreg[i] = h2f(u16p[(size_t)(b * 32 + (n >> 4)) * 4096 + 2560
                           + ((n & 15) << 6) + tt]);
    }

    // per-thread E slice: rows [jh*32,+32), cols [ch*6,+6) as 96 us2
    const int jh = tid >> 8;             // row half 0/1
    const int ch = tid & 255;            // 6-col chunk
    us2 ebv[96];
    {
        const size_t ebase = (size_t)(b * 64 + jh * 32) * 4096 + 1024 + ch * 6;
        #pragma unroll
        for (int r = 0; r < 32; ++r) {
            const unsigned short* p = u16p + ebase + (size_t)r * 4096;
            ebv[r * 3 + 0] = *reinterpret_cast<const us2*>(p);
            ebv[r * 3 + 1] = *reinterpret_cast<const us2*>(p + 2);
            ebv[r * 3 + 2] = *reinterpret_cast<const us2*>(p + 4);
        }
    }
    __syncthreads();
    // p_base = sum_{n in tq range} V[n] = -0.5 * sum Vm2
    float pbase = 0.0f;
    for (int i = 0; i < 64; ++i) pbase += Vm2[tq * 64 + i];
    pbase *= -0.5f;

    for (int t = 0; t < 64; ++t) {
        // ---- EMBX prefetch for this step (consumed in gates at step end)
        const int tok = tokL[t];
        const size_t eb = (size_t)(8192 + tok) * 4096 + 2560;
        const unsigned short exz = u16p[eb + tid];
        const unsigned short exr = u16p[eb + 512 + tid];
        const unsigned short exh = u16p[eb + 1024 + tid];
        // ---- q2[c] = (hs @ W2 + b2) * TLN2E via packed fp16 dot2
        {
            float a0 = 0.0f, a1 = 0.0f;
            #pragma unroll 4
            for (int k8 = 0; k8 < 64; k8 += 2) {
                union { us8 u; f16x2 p[4]; } w0, w1, h0, h1;
                w0.u = *reinterpret_cast<const us8*>(u16p + w2base + (size_t)k8 * 16384);
                w1.u = *reinterpret_cast<const us8*>(u16p + w2base + (size_t)(k8 + 1) * 16384);
                h0.u = *reinterpret_cast<const us8*>(&hsH[k8 * 8]);
                h1.u = *reinterpret_cast<const us8*>(&hsH[k8 * 8 + 8]);
                #pragma unroll
                for (int p = 0; p < 4; ++p) {
                    a0 = fdot2f(w0.p[p], h0.p[p], a0);
                    a1 = fdot2f(w1.p[p], h1.p[p], a1);
                }
            }
            qs2[tid] = (a0 + a1 + b2c) * TLN2E;
        }
        __syncthreads();                               // B1: qs2
        // ---- score partials: p = sumV + sum Vm2[n]/(exp2(k'+q')+1)
        {
            float p = pbase;
            #pragma unroll
            for (int i = 0; i < 64; ++i) {
                const int n = tq * 64 + i;
                const float e = aexp2(kreg[i] + qs2[n]);
                const float r = arcp(e + 1.0f);
                p = fmaf(Vm2[n], r, p);
            }
            part[tq][tt] = p;
        }
        __syncthreads();                               // B2: part
        // ---- redundant all-wave softmax: lane L owns tt=L (same in all 8 waves)
        {
            const int L = tid & 63;
            float sc = bVv;
            #pragma unroll
            for (int q8 = 0; q8 < 8; ++q8) sc += part[q8][L];
            float m = sc;
            m = fmaxf(m, __shfl_xor(m, 1));
            m = fmaxf(m, __shfl_xor(m, 2));
            m = fmaxf(m, __shfl_xor(m, 4));
            m = fmaxf(m, __shfl_xor(m, 8));
            m = fmaxf(m, __shfl_xor(m, 16));
            m = fmaxf(m, __shfl_xor(m, 32));
            const float ev = __expf(sc - m);
            float s = ev;
            s += __shfl_xor(s, 1);
            s += __shfl_xor(s, 2);
            s += __shfl_xor(s, 4);
            s += __shfl_xor(s, 8);
            s += __shfl_xor(s, 16);
            s += __shfl_xor(s, 32);
            wv[L] = ev / s;        // identical value from every wave
        }
        __syncthreads();                               // B3: wv
        // ---- xp_top partials: weighted sum of register-resident E rows
        {
            float a0 = 0, a1 = 0, a2 = 0, a3 = 0, a4 = 0, a5 = 0;
            const float* wvp = &wv[jh * 32];
            #pragma unroll
            for (int r = 0; r < 32; ++r) {
                const float w = wvp[r];
                const us2 e0 = ebv[r * 3 + 0];
                const us2 e1 = ebv[r * 3 + 1];
                const us2 e2 = ebv[r * 3 + 2];
                a0 += w * h2f(e0[0]); a1 += w * h2f(e0[1]);
                a2 += w * h2f(e1[0]); a3 += w * h2f(e1[1]);
                a4 += w * h2f(e2[0]); a5 += w * h2f(e2[1]);
            }
            float* xq = &xpP[jh][ch * 6];
            xq[0] = a0; xq[1] = a1; xq[2] = a2;
            xq[3] = a3; xq[4] = a4; xq[5] = a5;
        }
        __syncthreads();                               // B4: xpP
        // ---- xp = EMBX[tok] + (xpP[0]+xpP[1]); gates (h_prev = 0)
        {
            const float xz = h2f(exz) + (xpP[0][tid]        + xpP[1][tid]);
            const float xr = h2f(exr) + (xpP[0][512 + tid]  + xpP[1][512 + tid]);
            const float xh = h2f(exh) + (xpP[0][1024 + tid] + xpP[1][1024 + tid]);
            const float z = sigm(xz + bhz), r = sigm(xr + bhr);
            const float h = (1.0f - z) * tanhf(xh + r * bhn);
            hsH[tid] = f2h(h);
            erow[t * 2048 + tid] = h;
        }
        __syncthreads();                               // B5: hsH
    }
}

// ---------------------------------------------------------------------------
// logits = h @ Wfc + bfc via MFMA, in place. Block owns 64 FULL rows; A (h)
// staged to LDS before any write; B staged per 64-col tile from the READ-ONLY
// input Wfc (fp32->fp16), so no d_out weight region is read here.
// ---------------------------------------------------------------------------
__global__ __launch_bounds__(256)
void logits_m(float* __restrict__ out, const float* __restrict__ Wfc,
              const float* __restrict__ bfc)
{
    const int tid = threadIdx.x;
    const int wid = tid >> 6, lane = tid & 63;
    const int row16 = lane & 15, kg = lane >> 4;
    const int m0 = blockIdx.x * 64;

    __shared__ __align__(16) char aL[65536];   // [64 m][512 k] fp16 swizzled
    __shared__ __align__(16) char bL[65536];   // [64 n][512 k] fp16 swizzled

    for (int i = tid; i < 8192; i += 256) {
        const int m = i >> 7, k4 = (i & 127) << 2;
        const float4 v = *reinterpret_cast<const float4*>(out + (size_t)(m0 + m) * 2048 + k4);
        union { unsigned long long u64; _Float16 h[4]; } p;
        p.h[0] = (_Float16)v.x; p.h[1] = (_Float16)v.y;
        p.h[2] = (_Float16)v.z; p.h[3] = (_Float16)v.w;
        const int off = (m * 1024 + k4 * 2) ^ ((m & 7) << 4);
        *reinterpret_cast<unsigned long long*>(aL + off) = p.u64;
    }

    for (int nt = 0; nt < 32; ++nt) {
        const int n0t = nt * 64;
        __syncthreads();           // prior-iter bL reads done (and A-stage at nt=0)
        for (int i = tid; i < 8192; i += 256) {
            const int k = i >> 4, n4 = (i & 15) << 2;
            const float4 v = *reinterpret_cast<const float4*>(Wfc + (size_t)k * 2048 + n0t + n4);
            const int k2 = k * 2;
            *reinterpret_cast<_Float16*>(bL + (((n4 + 0) * 1024 + k2) ^ (((n4 + 0) & 7) << 4))) = (_Float16)v.x;
            *reinterpret_cast<_Float16*>(bL + (((n4 + 1) * 1024 + k2) ^ (((n4 + 1) & 7) << 4))) = (_Float16)v.y;
            *reinterpret_cast<_Float16*>(bL + (((n4 + 2) * 1024 + k2) ^ (((n4 + 2) & 7) << 4))) = (_Float16)v.z;
            *reinterpret_cast<_Float16*>(bL + (((n4 + 3) * 1024 + k2) ^ (((n4 + 3) & 7) << 4))) = (_Float16)v.w;
        }
        __syncthreads();

        f32x4 acc[4];
        #pragma unroll
        for (int ni = 0; ni < 4; ++ni) {
            f32x4 z = {0.f, 0.f, 0.f, 0.f};
            acc[ni] = z;
        }
        #pragma unroll 2
        for (int k0 = 0; k0 < 512; k0 += 32) {
            const int row = wid * 16 + row16;
            const int aoff = (row * 1024 + (k0 + kg * 8) * 2) ^ ((row & 7) << 4);
            const f16x8 af = *reinterpret_cast<const f16x8*>(aL + aoff);
            #pragma unroll
            for (int ni = 0; ni < 4; ++ni) {
                const int nr = ni * 16 + row16;
                const int boff = (nr * 1024 + (k0 + kg * 8) * 2) ^ ((nr & 7) << 4);
                const f16x8 bf_ = *reinterpret_cast<const f16x8*>(bL + boff);
                acc[ni] = __builtin_amdgcn_mfma_f32_16x16x32_f16(af, bf_, acc[ni], 0, 0, 0);
            }
        }
        #pragma unroll
        for (int ni = 0; ni < 4; ++ni) {
            const int n = n0t + ni * 16 + row16;
            const float bv = bfc[n];
            #pragma unroll
            for (int r = 0; r < 4; ++r)
                out[(size_t)(m0 + wid * 16 + kg * 4 + r) * 2048 + n] = acc[ni][r] + bv;
        }
    }
}

// ---------------------------------------------------------------------------
extern "C" void kernel_launch(void* const* d_in, const int* in_sizes, int n_in,
                              void* d_out, int out_size, void* d_ws, size_t ws_size,
                              hipStream_t stream) {
    (void)in_sizes; (void)n_in; (void)out_size; (void)d_ws; (void)ws_size;
    const float* enc_input = (const float*)d_in[0];
    const float* bn_e_g    = (const float*)d_in[1];
    const float* bn_e_b    = (const float*)d_in[2];
    const float* Wx_f      = (const float*)d_in[3];
    const float* Wh_f      = (const float*)d_in[4];
    const float* bx_f      = (const float*)d_in[5];
    const float* bh_f      = (const float*)d_in[6];
    const float* Wx_b      = (const float*)d_in[7];
    const float* Wh_b      = (const float*)d_in[8];
    const float* bx_b      = (const float*)d_in[9];
    const float* bh_b      = (const float*)d_in[10];
    const float* W1        = (const float*)d_in[11];
    const float* b1        = (const float*)d_in[12];
    const float* W2        = (const float*)d_in[13];
    const float* b2        = (const float*)d_in[14];
    const float* V         = (const float*)d_in[15];
    const float* bV        = (const float*)d_in[16];
    const float* emb       = (const float*)d_in[17];
    const float* bn_d_g    = (const float*)d_in[18];
    const float* bn_d_b    = (const float*)d_in[19];
    const float* Wx_d      = (const float*)d_in[20];
    // d_in[21] = Wh_d unused (decoder GRU runs with h_prev = 0)
    const float* bx_d      = (const float*)d_in[22];
    const float* bh_d      = (const float*)d_in[23];
    const float* Wfc       = (const float*)d_in[24];
    const float* bfc       = (const float*)d_in[25];
    const int*   targ      = (const int*)d_in[26];

    float* out = (float*)d_out;

    // 0. pack encoder weights fp16 (rows 11520..11951)
    repack_enc<<<dim3(864), dim3(512), 0, stream>>>(out, Wh_f, Wh_b, Wx_f, Wx_b);
    // 1. encoder -> enc slots (fp32 cols 0..511); Wh register-resident
    enc_gru<<<dim3(256), dim3(768), 0, stream>>>(
        enc_input, bn_e_g, bn_e_b, bx_f, bh_f, bx_b, bh_b, out);
    // 2. token table -> EMBX fp16 (rows 8192..10239)
    embx_k<<<dim3(128, 3), dim3(256), 0, stream>>>(out, emb, bn_d_g, bn_d_b, Wx_d, bx_d);
    // 3. pack W2 / Bp(=Wxd_top*sg, transposed) / W1p to fp16
    repack_k<<<dim3(2560), dim3(512), 0, stream>>>(out, W2, Wx_d, W1, bn_d_g);
    // 4. attention keys via MFMA -> keysT fp16 (pre-scaled by 2*log2e)
    gemm64<2><<<dim3(256), dim3(256), 0, stream>>>(out, b1);
    // 5. E = (enc*g1)@Wxd_top via MFMA -> fp16 (u16 cols 1024..2559)
    gemm64<0><<<dim3(256), dim3(256), 0, stream>>>(out, b1);
    // 6. decoder recurrence (keys+E register-resident, exp2 tanh, dot2 q)
    decoder<<<dim3(256), dim3(512), 0, stream>>>(out, b2, V, bV, bh_d, targ);
    // 7. logits via MFMA, in place (B from read-only Wfc input)
    logits_m<<<dim3(256), dim3(256), 0, stream>>>(out, Wfc, bfc);
}

// Round 11
// 1787.816 us; speedup vs baseline: 1.4690x; 1.4690x over previous
//
#include <hip/hip_runtime.h>

// B=256, T=64, F=32, ENC_U=256, DEC_U=512, VOCAB=2048, EMB=512, EPS=1e-3
// d_out = [16384 rows][2048 fp32 cols] = [16384][4096 u16 cols]. Region map:
//   fp32 cols    0..511 , all rows      : enc_out -> overwritten by decoder h
//   u16  cols 1024..2559, all rows      : E (fp16)  E[b,t'] = (enc*g1*INV)@Wxd_top
//   u16  cols 2560..3583, rows 0..8191  : keysT fp16 SCALED by 2*log2(e),
//                                         K=b*32768+n*64+tt -> row b*32+(n>>4)
//   u16  cols 2560..4095, rows 8192..10239 : EMBX fp16 [2048][1536]
//   u16  cols 2560..3583, rows 10240..10495: W2p  fp16 packed [k8][c][8]
//   u16  cols 2560..3583, rows 10496..11263: Bp   fp16 [n][k] = Wxd_top[k][n]*sg[k]
//   u16  cols 2560..3583, rows 11264..11519: W1p  fp16 [n][k] = W1[k][n]
//   u16  cols 2560..3583, rows 11520..11903: WhTp fp16 [dir][u][g][up] (encoder)
//   u16  cols 2560..3583, rows 11904..11951: WxTp fp16 [dir][g][fp][u][2]
// d_ws is not used.
// TOOLCHAIN INVARIANT (rounds 2,4,5,6,9): 512-thread kernels are capped at
// 128 VGPRs regardless of launch_bounds/waves_per_eu; register-resident
// per-thread data must stay <= ~96 or it spills (FETCH_SIZE blowup).
static constexpr float INV_SQ = 0.99950037468777319f;  // 1/sqrt(1+1e-3)
static constexpr float TLN2E  = 2.8853900817779268f;   // 2*log2(e)

typedef __attribute__((ext_vector_type(8))) unsigned short us8;
typedef __attribute__((ext_vector_type(2))) unsigned short us2;
typedef __attribute__((ext_vector_type(8))) _Float16 f16x8;
typedef __attribute__((ext_vector_type(2))) _Float16 f16x2;
typedef __attribute__((ext_vector_type(4))) float f32x4;

__device__ __forceinline__ float h2f(unsigned short u) {
    union { unsigned short q; _Float16 h; } cv; cv.q = u; return (float)cv.h;
}
__device__ __forceinline__ unsigned short f2h(float x) {
    union { _Float16 h; unsigned short u; } cv; cv.h = (_Float16)x; return cv.u;
}
__device__ __forceinline__ float sigm(float x) { return 1.0f / (1.0f + __expf(-x)); }
__device__ __forceinline__ float fdot2f(f16x2 a, f16x2 b, float c) {
#if __has_builtin(__builtin_amdgcn_fdot2)
    return __builtin_amdgcn_fdot2(a, b, c, false);
#else
    return c + (float)a[0] * (float)b[0] + (float)a[1] * (float)b[1];
#endif
}
__device__ __forceinline__ float aexp2(float x) {
#if __has_builtin(__builtin_amdgcn_exp2f)
    return __builtin_amdgcn_exp2f(x);
#else
    return exp2f(x);
#endif
}
__device__ __forceinline__ float arcp(float x) {
#if __has_builtin(__builtin_amdgcn_rcpf)
    return __builtin_amdgcn_rcpf(x);
#else
    return 1.0f / x;
#endif
}

// ---------------------------------------------------------------------------
// Pack encoder weights fp16 into d_out (before enc_gru).
// ---------------------------------------------------------------------------
__global__ __launch_bounds__(512)
void repack_enc(float* __restrict__ out,
                const float* __restrict__ WhF, const float* __restrict__ WhB,
                const float* __restrict__ WxF, const float* __restrict__ WxB)
{
    unsigned short* up = (unsigned short*)out;
    const int id = blockIdx.x * 512 + threadIdx.x;   // grid 864 -> 442368
    if (id < 393216) {
        const int dir = (id >= 196608) ? 1 : 0;
        const int r = id - dir * 196608;
        const int u = r / 768;
        const int rr = r - u * 768;
        const int g = rr >> 8, upp = rr & 255;
        const float v = (dir ? WhB : WhF)[upp * 768 + g * 256 + u];
        up[(size_t)(11520 + (id >> 10)) * 4096 + 2560 + (id & 1023)] = f2h(v);
    } else if (id < 442368) {
        const int x = id - 393216;
        const int dir = (x >= 24576) ? 1 : 0;
        const int r = x - dir * 24576;
        const int g = r >> 13;
        const int r2 = r & 8191;
        const int fp = r2 >> 9;
        const int r3 = r2 & 511;
        const int u = r3 >> 1, j = r3 & 1;
        const float v = (dir ? WxB : WxF)[(fp * 2 + j) * 768 + g * 256 + u];
        up[(size_t)(11904 + (x >> 10)) * 4096 + 2560 + (x & 1023)] = f2h(v);
    }
}

// ---------------------------------------------------------------------------
// Encoder: persistent bidirectional GRU, 768 threads = (u, gate).
// Wh slice register-resident (32 us8/thread); h fp16 in LDS for dot2;
// GRU memory path fp32 in hsF; Wx fp16 staged in LDS.
// ---------------------------------------------------------------------------
__global__ __launch_bounds__(768, 1)
void enc_gru(const float* __restrict__ x,
             const float* __restrict__ g_e, const float* __restrict__ b_e,
             const float* __restrict__ bxF, const float* __restrict__ bhF,
             const float* __restrict__ bxB, const float* __restrict__ bhB,
             float* __restrict__ out)
{
    const int tid = threadIdx.x;
    const int dir = blockIdx.x & 1;
    const int b0  = (blockIdx.x >> 1) * 2;
    const int u = tid & 255, g = tid >> 8;   // g in 0..2

    const float* bx = dir ? bxB : bxF;
    const float* bh = dir ? bhB : bhF;

    __shared__ us2 WxL[12288];                           // [g][fp][u] 48 KiB
    __shared__ __align__(16) unsigned short hsH[2][256]; // h fp16 (matvec in)
    __shared__ float hsF[2][256];                        // h fp32 (memory path)
    __shared__ float part[4][2][256];                    // z, r, nx, nh
    __shared__ __align__(16) unsigned short xsH[2][32];

    const unsigned short* u16p = (const unsigned short*)out;

    for (int i = 0; i < 16; ++i) {
        const int fi = dir * 24576 + (tid * 16 + i) * 2;   // u16 flat
        const size_t a = (size_t)(11904 + (fi >> 10)) * 4096 + 2560 + (fi & 1023);
        WxL[tid * 16 + i] = *reinterpret_cast<const us2*>(u16p + a);
    }
    us8 ebw[32];
    {
        const int base = dir * 196608 + (u * 3 + g) * 256;   // u16 flat
        #pragma unroll
        for (int k = 0; k < 32; ++k) {
            const int fi = base + k * 8;
            const size_t a = (size_t)(11520 + (fi >> 10)) * 4096 + 2560 + (fi & 1023);
            ebw[k] = *reinterpret_cast<const us8*>(u16p + a);
        }
    }
    if (tid < 256) {
        hsF[0][tid] = 0.0f; hsF[1][tid] = 0.0f;
        hsH[0][tid] = 0;    hsH[1][tid] = 0;
    }
    const float bxg = bx[g * 256 + u], bhg = bh[g * 256 + u];
    __syncthreads();

    for (int t = 0; t < 64; ++t) {
        const int ts = dir ? (63 - t) : t;
        if (tid < 64) {
            const int f = tid & 31, bs = tid >> 5;
            xsH[bs][f] = f2h(x[((b0 + bs) * 64 + ts) * 32 + f] * (g_e[f] * INV_SQ) + b_e[f]);
        }
        __syncthreads();                                   // B1: xsH (+prev hsH)

        float ax0 = bxg, ax1 = bxg, ah0 = bhg, ah1 = bhg;
        {
            const us2* xs0 = reinterpret_cast<const us2*>(&xsH[0][0]);
            const us2* xs1 = reinterpret_cast<const us2*>(&xsH[1][0]);
            #pragma unroll
            for (int fp = 0; fp < 16; ++fp) {
                union { us2 q; f16x2 h; } w, a0, a1;
                w.q = WxL[(g * 16 + fp) * 256 + u];
                a0.q = xs0[fp]; a1.q = xs1[fp];
                ax0 = fdot2f(w.h, a0.h, ax0);
                ax1 = fdot2f(w.h, a1.h, ax1);
            }
        }
        #pragma unroll
        for (int k = 0; k < 32; ++k) {
            union { us8 q; f16x2 p[4]; } w, h0, h1;
            w.q = ebw[k];
            h0.q = *reinterpret_cast<const us8*>(&hsH[0][k * 8]);
            h1.q = *reinterpret_cast<const us8*>(&hsH[1][k * 8]);
            #pragma unroll
            for (int j = 0; j < 4; ++j) {
                ah0 = fdot2f(w.p[j], h0.p[j], ah0);
                ah1 = fdot2f(w.p[j], h1.p[j], ah1);
            }
        }
        if (g < 2) {
            part[g][0][u] = ax0 + ah0;
            part[g][1][u] = ax1 + ah1;
        } else {
            part[2][0][u] = ax0; part[2][1][u] = ax1;   // xh + bx_h
            part[3][0][u] = ah0; part[3][1][u] = ah1;   // hn + bh_n
        }
        __syncthreads();                                   // B2: part
        if (tid < 512) {
            const int bs = tid >> 8, uu = tid & 255;
            const float z = sigm(part[0][bs][uu]);
            const float r = sigm(part[1][bs][uu]);
            const float n = tanhf(part[2][bs][uu] + r * part[3][bs][uu]);
            const float hp = hsF[bs][uu];
            const float h = z * hp + (1.0f - z) * n;
            hsF[bs][uu] = h;
            hsH[bs][uu] = f2h(h);
            out[((b0 + bs) * 64 + ts) * 2048 + dir * 256 + uu] = h;
        }
        __syncthreads();                                   // B3: hsH/hsF
    }
}

// ---------------------------------------------------------------------------
// EMBX[v,n] = ((emb[v]*g2+beta2) @ Wxd_bot)[n] + (beta1 @ Wxd_top)[n] + bx_d[n]
// fp16 at row 8192+v, u16 col 2560+n. grid (128,3).
// ---------------------------------------------------------------------------
__global__ __launch_bounds__(256)
void embx_k(float* __restrict__ out, const float* __restrict__ emb,
            const float* __restrict__ g, const float* __restrict__ be,
            const float* __restrict__ Wxd, const float* __restrict__ bxd)
{
    __shared__ __align__(16) float As[16 * 512];
    const int tid = threadIdx.x;
    const int r0  = blockIdx.x * 16;
    const int n0  = blockIdx.y * 512;

    #pragma unroll
    for (int i = 0; i < 32; ++i) {
        const int idx = tid + i * 256;
        const int r = idx >> 9, k = idx & 511;
        As[idx] = emb[(r0 + r) * 512 + k] * (g[512 + k] * INV_SQ) + be[512 + k];
    }
    __syncthreads();

    const int n1 = n0 + tid, n2 = n0 + tid + 256;
    float cv1 = bxd[n1], cv2 = bxd[n2];
    for (int i = 0; i < 512; ++i) {
        const float bi = be[i];
        cv1 += bi * Wxd[i * 1536 + n1];
        cv2 += bi * Wxd[i * 1536 + n2];
    }

    float acc1[16], acc2[16];
    #pragma unroll
    for (int r = 0; r < 16; ++r) { acc1[r] = cv1; acc2[r] = cv2; }

    for (int k = 0; k < 512; k += 4) {
        float w1[4], w2[4];
        #pragma unroll
        for (int kk = 0; kk < 4; ++kk) {
            w1[kk] = Wxd[(512 + k + kk) * 1536 + n1];
            w2[kk] = Wxd[(512 + k + kk) * 1536 + n2];
        }
        #pragma unroll
        for (int r = 0; r < 16; ++r) {
            const float4 a = *reinterpret_cast<const float4*>(&As[r * 512 + k]);
            acc1[r] += a.x * w1[0] + a.y * w1[1] + a.z * w1[2] + a.w * w1[3];
            acc2[r] += a.x * w2[0] + a.y * w2[1] + a.z * w2[2] + a.w * w2[3];
        }
    }

    unsigned short* up = (unsigned short*)out;
    #pragma unroll
    for (int r = 0; r < 16; ++r) {
        const size_t base = (size_t)(8192 + r0 + r) * 4096 + 2560;
        up[base + n1] = f2h(acc1[r]);
        up[base + n2] = f2h(acc2[r]);
    }
}

// ---------------------------------------------------------------------------
// Repack weights into fp16 tiles inside d_out.
// ---------------------------------------------------------------------------
__global__ __launch_bounds__(512)
void repack_k(float* __restrict__ out, const float* __restrict__ W2,
              const float* __restrict__ Wxd, const float* __restrict__ W1,
              const float* __restrict__ g1)
{
    unsigned short* up = (unsigned short*)out;
    const int id = blockIdx.x * 512 + threadIdx.x;   // grid 2560 -> 1,310,720
    if (id < 262144) {
        const int k8 = id >> 12, rem = id & 4095, c = rem >> 3, j = rem & 7;
        up[(size_t)(10240 + (id >> 10)) * 4096 + 2560 + (id & 1023)] =
            f2h(W2[(k8 * 8 + j) * 512 + c]);
    } else if (id < 1048576) {
        const int x = id - 262144;
        const int n = x >> 9, k = x & 511;
        up[(size_t)(10496 + (x >> 10)) * 4096 + 2560 + (x & 1023)] =
            f2h(Wxd[k * 1536 + n] * (g1[k] * INV_SQ));
    } else {
        const int x = id - 1048576;
        const int n = x >> 9, k = x & 511;
        up[(size_t)(11264 + (x >> 10)) * 4096 + 2560 + (x & 1023)] =
            f2h(W1[k * 512 + n]);
    }
}

// ---------------------------------------------------------------------------
// MFMA GEMM, 64-row A tile (enc rows, fp32 cols 0..511 -> fp16 LDS, swizzled).
// MODE 0: E = enc @ Bp           -> fp16, u16 col 1024+n, same row.   NT=24
// MODE 2: keysT = (enc @ W1p + b1)*TLN2E -> fp16 transposed keysT.    NT=8
//         (scale folds tanh's 2*log2e into the stored keys; consumed
//          ONLY by the decoder score phase)
// ---------------------------------------------------------------------------
template <int MODE>
__global__ __launch_bounds__(256, 2)
void gemm64(float* __restrict__ out, const float* __restrict__ bias)
{
    constexpr int NT   = (MODE == 0) ? 24 : 8;
    constexpr int BROW = (MODE == 0) ? 10496 : 11264;
    const int tid = threadIdx.x;
    const int wid = tid >> 6, lane = tid & 63;
    const int row16 = lane & 15, kg = lane >> 4;
    const int m0 = blockIdx.x * 64;
    const unsigned short* u16p = (const unsigned short*)out;
    unsigned short* up = (unsigned short*)out;

    __shared__ __align__(16) char aL[65536];   // [64 m][512 k] fp16, xor-swizzled

    for (int i = tid; i < 8192; i += 256) {
        const int m = i >> 7, k4 = (i & 127) << 2;
        const float4 v = *reinterpret_cast<const float4*>(out + (size_t)(m0 + m) * 2048 + k4);
        union { unsigned long long u64; _Float16 h[4]; } p;
        p.h[0] = (_Float16)v.x; p.h[1] = (_Float16)v.y;
        p.h[2] = (_Float16)v.z; p.h[3] = (_Float16)v.w;
        const int off = (m * 1024 + k4 * 2) ^ ((m & 7) << 4);
        *reinterpret_cast<unsigned long long*>(aL + off) = p.u64;
    }
    __syncthreads();

    for (int i = 0; i < NT / 4; ++i) {
        const int nt = i * 4 + wid;
        const int n0t = nt * 64;
        f32x4 acc[4][4];
        #pragma unroll
        for (int mi = 0; mi < 4; ++mi)
            #pragma unroll
            for (int ni = 0; ni < 4; ++ni) {
                f32x4 z = {0.f, 0.f, 0.f, 0.f};
                acc[mi][ni] = z;
            }
        size_t bb[4];
        #pragma unroll
        for (int ni = 0; ni < 4; ++ni) {
            const int n = n0t + ni * 16 + row16;
            bb[ni] = (size_t)(BROW + (n >> 1)) * 4096 + 2560 + (n & 1) * 512 + kg * 8;
        }
        #pragma unroll 2
        for (int k0 = 0; k0 < 512; k0 += 32) {
            f16x8 af[4], bfr[4];
            #pragma unroll
            for (int mi = 0; mi < 4; ++mi) {
                const int row = mi * 16 + row16;
                const int off = (row * 1024 + (k0 + kg * 8) * 2) ^ ((row & 7) << 4);
                af[mi] = *reinterpret_cast<const f16x8*>(aL + off);
            }
            #pragma unroll
            for (int ni = 0; ni < 4; ++ni)
                bfr[ni] = *reinterpret_cast<const f16x8*>(u16p + bb[ni] + k0);
            #pragma unroll
            for (int mi = 0; mi < 4; ++mi)
                #pragma unroll
                for (int ni = 0; ni < 4; ++ni)
                    acc[mi][ni] = __builtin_amdgcn_mfma_f32_16x16x32_f16(
                        af[mi], bfr[ni], acc[mi][ni], 0, 0, 0);
        }
        #pragma unroll
        for (int mi = 0; mi < 4; ++mi) {
            #pragma unroll
            for (int ni = 0; ni < 4; ++ni) {
                const int n = n0t + ni * 16 + row16;
                if constexpr (MODE == 0) {
                    #pragma unroll
                    for (int r = 0; r < 4; ++r)
                        up[(size_t)(m0 + mi * 16 + kg * 4 + r) * 4096 + 1024 + n] =
                            f2h(acc[mi][ni][r]);
                } else {
                    const float bv = bias[n];
                    #pragma unroll
                    for (int r = 0; r < 4; ++r) {
                        const int ttm = mi * 16 + kg * 4 + r;
                        up[(size_t)(blockIdx.x * 32 + (n >> 4)) * 4096 + 2560 +
                           ((n & 15) << 6) + ttm] = f2h((acc[mi][ni][r] + bv) * TLN2E);
                    }
                }
            }
        }
    }
}

// ---------------------------------------------------------------------------
// Decoder: persistent per-batch, 512 threads, launch_bounds(512,1).
// Round-8 structure (keysL in LDS, ebv[96] registers -> fits the 128-VGPR
// toolchain cap, FETCH ~53 MB) + round-9 algebra (register-neutral):
//  - keysT pre-scaled by 2*log2e; score tanh via exp2+rcp, no clamp,
//    sum(V) hoisted into pbase, Vm2 = -2V.
//  - q matvec via v_dot2_f32_f16; all-wave shuffle softmax; EMBX prefetch.
// ---------------------------------------------------------------------------
__global__ __launch_bounds__(512, 1)
void decoder(float* __restrict__ out,
             const float* __restrict__ b2,
             const float* __restrict__ V, const float* __restrict__ bV,
             const float* __restrict__ bh_d, const int* __restrict__ targ)
{
    const int b = blockIdx.x, tid = threadIdx.x;
    __shared__ __align__(16) unsigned short keysL[32768];   // fp16 [n][tt] 64 KiB
    __shared__ __align__(16) unsigned short hsH[512];       // h as fp16
    __shared__ float qs2[512], Vm2[512];
    __shared__ float part[8][64], wv[64];
    __shared__ float xpP[2][1536];
    __shared__ int   tokL[64];

    float* erow = out + (size_t)b * 131072;
    const unsigned short* u16p = (const unsigned short*)out;

    #pragma unroll
    for (int i8 = tid * 8; i8 < 32768; i8 += 4096)
        *reinterpret_cast<us8*>(&keysL[i8]) =
            *reinterpret_cast<const us8*>(u16p + (size_t)(b * 32 + (i8 >> 10)) * 4096
                                          + 2560 + (i8 & 1023));

    // dec_h0 = concat(fwd final (t=63, cols<256), bwd final (t=0, cols>=256))
    hsH[tid] = f2h((tid < 256) ? erow[63 * 2048 + tid] : erow[tid]);
    Vm2[tid] = -2.0f * V[tid];
    if (tid < 64) tokL[tid] = targ[b * 64 + tid];
    const float b2c = b2[tid];
    const float bhz = bh_d[tid], bhr = bh_d[512 + tid], bhn = bh_d[1024 + tid];
    const float bVv = bV[0];
    const int lo7 = tid & 127, hi3 = tid >> 7;
    const size_t w2base = (size_t)(10240 + hi3) * 4096 + 2560 + lo7 * 8;
    const int tt = tid & 63, tq = tid >> 6;

    // per-thread E slice: rows [jh*32,+32), cols [ch*6,+6) as 96 us2
    const int jh = tid >> 8;             // row half 0/1
    const int ch = tid & 255;            // 6-col chunk
    us2 ebv[96];
    {
        const size_t ebase = (size_t)(b * 64 + jh * 32) * 4096 + 1024 + ch * 6;
        #pragma unroll
        for (int r = 0; r < 32; ++r) {
            const unsigned short* p = u16p + ebase + (size_t)r * 4096;
            ebv[r * 3 + 0] = *reinterpret_cast<const us2*>(p);
            ebv[r * 3 + 1] = *reinterpret_cast<const us2*>(p + 2);
            ebv[r * 3 + 2] = *reinterpret_cast<const us2*>(p + 4);
        }
    }
    __syncthreads();
    // p_base = sum_{n in tq range} V[n] = -0.5 * sum Vm2
    float pbase = 0.0f;
    for (int i = 0; i < 64; ++i) pbase += Vm2[tq * 64 + i];
    pbase *= -0.5f;

    for (int t = 0; t < 64; ++t) {
        // ---- EMBX prefetch for this step (consumed in gates at step end)
        const int tok = tokL[t];
        const size_t eb = (size_t)(8192 + tok) * 4096 + 2560;
        const unsigned short exz = u16p[eb + tid];
        const unsigned short exr = u16p[eb + 512 + tid];
        const unsigned short exh = u16p[eb + 1024 + tid];
        // ---- q2[c] = (hs @ W2 + b2) * TLN2E via packed fp16 dot2
        {
            float a0 = 0.0f, a1 = 0.0f;
            #pragma unroll 4
            for (int k8 = 0; k8 < 64; k8 += 2) {
                union { us8 u; f16x2 p[4]; } w0, w1, h0, h1;
                w0.u = *reinterpret_cast<const us8*>(u16p + w2base + (size_t)k8 * 16384);
                w1.u = *reinterpret_cast<const us8*>(u16p + w2base + (size_t)(k8 + 1) * 16384);
                h0.u = *reinterpret_cast<const us8*>(&hsH[k8 * 8]);
                h1.u = *reinterpret_cast<const us8*>(&hsH[k8 * 8 + 8]);
                #pragma unroll
                for (int p = 0; p < 4; ++p) {
                    a0 = fdot2f(w0.p[p], h0.p[p], a0);
                    a1 = fdot2f(w1.p[p], h1.p[p], a1);
                }
            }
            qs2[tid] = (a0 + a1 + b2c) * TLN2E;
        }
        __syncthreads();                               // B1: qs2
        // ---- score partials: p = sumV + sum Vm2[n]/(exp2(k'+q')+1)
        {
            float p = pbase;
            #pragma unroll 8
            for (int i = 0; i < 64; ++i) {
                const int n = tq * 64 + i;
                const float e = aexp2(h2f(keysL[n * 64 + tt]) + qs2[n]);
                p = fmaf(Vm2[n], arcp(e + 1.0f), p);
            }
            part[tq][tt] = p;
        }
        __syncthreads();                               // B2: part
        // ---- redundant all-wave softmax: lane L owns tt=L (same in all 8 waves)
        {
            const int L = tid & 63;
            float sc = bVv;
            #pragma unroll
            for (int q8 = 0; q8 < 8; ++q8) sc += part[q8][L];
            float m = sc;
            m = fmaxf(m, __shfl_xor(m, 1));
            m = fmaxf(m, __shfl_xor(m, 2));
            m = fmaxf(m, __shfl_xor(m, 4));
            m = fmaxf(m, __shfl_xor(m, 8));
            m = fmaxf(m, __shfl_xor(m, 16));
            m = fmaxf(m, __shfl_xor(m, 32));
            const float ev = __expf(sc - m);
            float s = ev;
            s += __shfl_xor(s, 1);
            s += __shfl_xor(s, 2);
            s += __shfl_xor(s, 4);
            s += __shfl_xor(s, 8);
            s += __shfl_xor(s, 16);
            s += __shfl_xor(s, 32);
            wv[L] = ev / s;        // identical value from every wave
        }
        __syncthreads();                               // B3: wv
        // ---- xp_top partials: weighted sum of register-resident E rows
        {
            float a0 = 0, a1 = 0, a2 = 0, a3 = 0, a4 = 0, a5 = 0;
            const float* wvp = &wv[jh * 32];
            #pragma unroll
            for (int r = 0; r < 32; ++r) {
                const float w = wvp[r];
                const us2 e0 = ebv[r * 3 + 0];
                const us2 e1 = ebv[r * 3 + 1];
                const us2 e2 = ebv[r * 3 + 2];
                a0 += w * h2f(e0[0]); a1 += w * h2f(e0[1]);
                a2 += w * h2f(e1[0]); a3 += w * h2f(e1[1]);
                a4 += w * h2f(e2[0]); a5 += w * h2f(e2[1]);
            }
            float* xq = &xpP[jh][ch * 6];
            xq[0] = a0; xq[1] = a1; xq[2] = a2;
            xq[3] = a3; xq[4] = a4; xq[5] = a5;
        }
        __syncthreads();                               // B4: xpP
        // ---- xp = EMBX[tok] + (xpP[0]+xpP[1]); gates (h_prev = 0)
        {
            const float xz = h2f(exz) + (xpP[0][tid]        + xpP[1][tid]);
            const float xr = h2f(exr) + (xpP[0][512 + tid]  + xpP[1][512 + tid]);
            const float xh = h2f(exh) + (xpP[0][1024 + tid] + xpP[1][1024 + tid]);
            const float z = sigm(xz + bhz), r = sigm(xr + bhr);
            const float h = (1.0f - z) * tanhf(xh + r * bhn);
            hsH[tid] = f2h(h);
            erow[t * 2048 + tid] = h;
        }
        __syncthreads();                               // B5: hsH
    }
}

// ---------------------------------------------------------------------------
// logits = h @ Wfc + bfc via MFMA, in place. Block owns 64 FULL rows; A (h)
// staged to LDS before any write; B staged per 64-col tile from the READ-ONLY
// input Wfc (fp32->fp16), so no d_out weight region is read here.
// ---------------------------------------------------------------------------
__global__ __launch_bounds__(256)
void logits_m(float* __restrict__ out, const float* __restrict__ Wfc,
              const float* __restrict__ bfc)
{
    const int tid = threadIdx.x;
    const int wid = tid >> 6, lane = tid & 63;
    const int row16 = lane & 15, kg = lane >> 4;
    const int m0 = blockIdx.x * 64;

    __shared__ __align__(16) char aL[65536];   // [64 m][512 k] fp16 swizzled
    __shared__ __align__(16) char bL[65536];   // [64 n][512 k] fp16 swizzled

    for (int i = tid; i < 8192; i += 256) {
        const int m = i >> 7, k4 = (i & 127) << 2;
        const float4 v = *reinterpret_cast<const float4*>(out + (size_t)(m0 + m) * 2048 + k4);
        union { unsigned long long u64; _Float16 h[4]; } p;
        p.h[0] = (_Float16)v.x; p.h[1] = (_Float16)v.y;
        p.h[2] = (_Float16)v.z; p.h[3] = (_Float16)v.w;
        const int off = (m * 1024 + k4 * 2) ^ ((m & 7) << 4);
        *reinterpret_cast<unsigned long long*>(aL + off) = p.u64;
    }

    for (int nt = 0; nt < 32; ++nt) {
        const int n0t = nt * 64;
        __syncthreads();           // prior-iter bL reads done (and A-stage at nt=0)
        for (int i = tid; i < 8192; i += 256) {
            const int k = i >> 4, n4 = (i & 15) << 2;
            const float4 v = *reinterpret_cast<const float4*>(Wfc + (size_t)k * 2048 + n0t + n4);
            const int k2 = k * 2;
            *reinterpret_cast<_Float16*>(bL + (((n4 + 0) * 1024 + k2) ^ (((n4 + 0) & 7) << 4))) = (_Float16)v.x;
            *reinterpret_cast<_Float16*>(bL + (((n4 + 1) * 1024 + k2) ^ (((n4 + 1) & 7) << 4))) = (_Float16)v.y;
            *reinterpret_cast<_Float16*>(bL + (((n4 + 2) * 1024 + k2) ^ (((n4 + 2) & 7) << 4))) = (_Float16)v.z;
            *reinterpret_cast<_Float16*>(bL + (((n4 + 3) * 1024 + k2) ^ (((n4 + 3) & 7) << 4))) = (_Float16)v.w;
        }
        __syncthreads();

        f32x4 acc[4];
        #pragma unroll
        for (int ni = 0; ni < 4; ++ni) {
            f32x4 z = {0.f, 0.f, 0.f, 0.f};
            acc[ni] = z;
        }
        #pragma unroll 2
        for (int k0 = 0; k0 < 512; k0 += 32) {
            const int row = wid * 16 + row16;
            const int aoff = (row * 1024 + (k0 + kg * 8) * 2) ^ ((row & 7) << 4);
            const f16x8 af = *reinterpret_cast<const f16x8*>(aL + aoff);
            #pragma unroll
            for (int ni = 0; ni < 4; ++ni) {
                const int nr = ni * 16 + row16;
                const int boff = (nr * 1024 + (k0 + kg * 8) * 2) ^ ((nr & 7) << 4);
                const f16x8 bf_ = *reinterpret_cast<const f16x8*>(bL + boff);
                acc[ni] = __builtin_amdgcn_mfma_f32_16x16x32_f16(af, bf_, acc[ni], 0, 0, 0);
            }
        }
        #pragma unroll
        for (int ni = 0; ni < 4; ++ni) {
            const int n = n0t + ni * 16 + row16;
            const float bv = bfc[n];
            #pragma unroll
            for (int r = 0; r < 4; ++r)
                out[(size_t)(m0 + wid * 16 + kg * 4 + r) * 2048 + n] = acc[ni][r] + bv;
        }
    }
}

// ---------------------------------------------------------------------------
extern "C" void kernel_launch(void* const* d_in, const int* in_sizes, int n_in,
                              void* d_out, int out_size, void* d_ws, size_t ws_size,
                              hipStream_t stream) {
    (void)in_sizes; (void)n_in; (void)out_size; (void)d_ws; (void)ws_size;
    const float* enc_input = (const float*)d_in[0];
    const float* bn_e_g    = (const float*)d_in[1];
    const float* bn_e_b    = (const float*)d_in[2];
    const float* Wx_f      = (const float*)d_in[3];
    const float* Wh_f      = (const float*)d_in[4];
    const float* bx_f      = (const float*)d_in[5];
    const float* bh_f      = (const float*)d_in[6];
    const float* Wx_b      = (const float*)d_in[7];
    const float* Wh_b      = (const float*)d_in[8];
    const float* bx_b      = (const float*)d_in[9];
    const float* bh_b      = (const float*)d_in[10];
    const float* W1        = (const float*)d_in[11];
    const float* b1        = (const float*)d_in[12];
    const float* W2        = (const float*)d_in[13];
    const float* b2        = (const float*)d_in[14];
    const float* V         = (const float*)d_in[15];
    const float* bV        = (const float*)d_in[16];
    const float* emb       = (const float*)d_in[17];
    const float* bn_d_g    = (const float*)d_in[18];
    const float* bn_d_b    = (const float*)d_in[19];
    const float* Wx_d      = (const float*)d_in[20];
    // d_in[21] = Wh_d unused (decoder GRU runs with h_prev = 0)
    const float* bx_d      = (const float*)d_in[22];
    const float* bh_d      = (const float*)d_in[23];
    const float* Wfc       = (const float*)d_in[24];
    const float* bfc       = (const float*)d_in[25];
    const int*   targ      = (const int*)d_in[26];

    float* out = (float*)d_out;

    // 0. pack encoder weights fp16 (rows 11520..11951)
    repack_enc<<<dim3(864), dim3(512), 0, stream>>>(out, Wh_f, Wh_b, Wx_f, Wx_b);
    // 1. encoder -> enc slots (fp32 cols 0..511); Wh register-resident
    enc_gru<<<dim3(256), dim3(768), 0, stream>>>(
        enc_input, bn_e_g, bn_e_b, bx_f, bh_f, bx_b, bh_b, out);
    // 2. token table -> EMBX fp16 (rows 8192..10239)
    embx_k<<<dim3(128, 3), dim3(256), 0, stream>>>(out, emb, bn_d_g, bn_d_b, Wx_d, bx_d);
    // 3. pack W2 / Bp(=Wxd_top*sg, transposed) / W1p to fp16
    repack_k<<<dim3(2560), dim3(512), 0, stream>>>(out, W2, Wx_d, W1, bn_d_g);
    // 4. attention keys via MFMA -> keysT fp16 (pre-scaled by 2*log2e)
    gemm64<2><<<dim3(256), dim3(256), 0, stream>>>(out, b1);
    // 5. E = (enc*g1)@Wxd_top via MFMA -> fp16 (u16 cols 1024..2559)
    gemm64<0><<<dim3(256), dim3(256), 0, stream>>>(out, b1);
    // 6. decoder recurrence (keys LDS, E register-resident, exp2 tanh)
    decoder<<<dim3(256), dim3(512), 0, stream>>>(out, b2, V, bV, bh_d, targ);
    // 7. logits via MFMA, in place (B from read-only Wfc input)
    logits_m<<<dim3(256), dim3(256), 0, stream>>>(out, Wfc, bfc);
}